// Round 3
// baseline (518.705 us; speedup 1.0000x reference)
//
#include <hip/hip_runtime.h>
#include <stdint.h>

#define KNN 16
#define LROWS 8
#define SCAP 512

// ---------------------------------------------------------------------------
// Prep kernels: batch bounds, SoA xyz (padded), per-query metadata.
// ---------------------------------------------------------------------------
__global__ void prep_bounds(const int* __restrict__ bidx, int N,
                            int* __restrict__ starts, int* __restrict__ ends) {
  int i = blockIdx.x * 256 + threadIdx.x;
  if (i >= N) return;
  int b = bidx[i];
  if (i == 0 || bidx[i - 1] != b) starts[b] = i;
  if (i == N - 1 || bidx[i + 1] != b) ends[b] = i + 1;
}

__global__ void prep_soa(const float* __restrict__ sxyz, float* __restrict__ xs,
                         float* __restrict__ ys, float* __restrict__ zs,
                         int N, int NP) {
  int i = blockIdx.x * 256 + threadIdx.x;
  if (i >= NP) return;
  float x = 0.f, y = 0.f, z = 0.f;
  if (i < N) { x = sxyz[3 * i]; y = sxyz[3 * i + 1]; z = sxyz[3 * i + 2]; }
  xs[i] = x; ys[i] = y; zs[i] = z;
}

__global__ void prep_qmeta(const float* __restrict__ sxyz,
                           const int* __restrict__ bidx,
                           const int* __restrict__ fidx,
                           const int* __restrict__ starts,
                           const int* __restrict__ ends,
                           float* __restrict__ qmeta, int Q) {
  int q = blockIdx.x * 256 + threadIdx.x;
  if (q >= Q) return;
  int fi = fidx[q];
  int b = bidx[fi];
  qmeta[8 * q + 0] = sxyz[3 * fi];
  qmeta[8 * q + 1] = sxyz[3 * fi + 1];
  qmeta[8 * q + 2] = sxyz[3 * fi + 2];
  qmeta[8 * q + 3] = __int_as_float(starts[b]);
  qmeta[8 * q + 4] = __int_as_float(ends[b]);
}

// ---------------------------------------------------------------------------
// KNN: 256 threads / query. Pass 1: per-lane min over its ~32-pt group ->
// 16th smallest of 256 group-minima is a provable upper bound on the true
// 16th-NN d2 (16 disjoint groups have min <= thr => >=16 pts <= thr).
// Pass 2: rescan (L1-hot), collect survivors (~17 expected, rank-stat
// distribution-free). Phase 3: exact top-16 by packed (d2,idx) key ==
// lax.top_k tie semantics.
// ---------------------------------------------------------------------------
template <bool SOA>
__global__ __launch_bounds__(256) void knn_kernel(
    const float* __restrict__ xs, const float* __restrict__ ys,
    const float* __restrict__ zs, const float* __restrict__ qmeta,
    const float* __restrict__ sxyz, const int* __restrict__ bidx,
    const int* __restrict__ fidx, int* __restrict__ col, int N) {
  const int q = blockIdx.x, t = threadIdx.x;
  float qx, qy, qz; int lo, hi;
  if (SOA) {
    float4 m = *(const float4*)&qmeta[8 * q];
    qx = m.x; qy = m.y; qz = m.z;
    lo = __float_as_int(m.w);
    hi = __float_as_int(qmeta[8 * q + 4]);
  } else {
    int fi = fidx[q];
    qx = sxyz[3 * fi]; qy = sxyz[3 * fi + 1]; qz = sxyz[3 * fi + 2];
    int qb = bidx[fi];
    int a = 0, b = N;
    while (a < b) { int m = (a + b) >> 1; if (bidx[m] < qb) a = m + 1; else b = m; }
    lo = a; b = N;
    while (a < b) { int m = (a + b) >> 1; if (bidx[m] <= qb) a = m + 1; else b = m; }
    hi = a;
  }

  __shared__ float s_min[256];
  __shared__ unsigned long long s_cand[SCAP];
  __shared__ int s_cnt;
  __shared__ float s_thr;
  if (t == 0) s_cnt = 0;

  // --- pass 1: group minima ---
  float gmin = 3e38f;
  if (SOA) {
    const int base = lo & ~3;
    for (int i0 = base + 4 * t; i0 < hi; i0 += 1024) {
      float4 vx = *(const float4*)&xs[i0];
      float4 vy = *(const float4*)&ys[i0];
      float4 vz = *(const float4*)&zs[i0];
#define ACC1(E, e)                                                  \
  { int i = i0 + E;                                                 \
    float dx = qx - vx.e, dy = qy - vy.e, dz = qz - vz.e;           \
    float d2 = fmaf(dx, dx, fmaf(dy, dy, dz * dz));                 \
    gmin = fminf(gmin, (i >= lo && i < hi) ? d2 : 3e38f); }
      ACC1(0, x) ACC1(1, y) ACC1(2, z) ACC1(3, w)
#undef ACC1
    }
  } else {
    for (int i = lo + t; i < hi; i += 256) {
      float dx = qx - sxyz[3 * i], dy = qy - sxyz[3 * i + 1], dz = qz - sxyz[3 * i + 2];
      gmin = fminf(gmin, fmaf(dx, dx, fmaf(dy, dy, dz * dz)));
    }
  }
  s_min[t] = gmin;
  __syncthreads();

  // --- 16th smallest of 256 group minima (wave 0, registers+shuffles) ---
  if (t < 64) {
    float c0 = s_min[t], c1 = s_min[t + 64], c2 = s_min[t + 128], c3 = s_min[t + 192];
    float thr = 3e38f;
    for (int r = 0; r < KNN; ++r) {
      float lm = fminf(fminf(c0, c1), fminf(c2, c3));
      float m = lm;
      for (int off = 32; off; off >>= 1) m = fminf(m, __shfl_xor(m, off, 64));
      unsigned long long ball = __ballot(lm == m);
      int win = __ffsll(ball) - 1;   // knock exactly one instance
      if (t == win) {
        if (c0 == m) c0 = 3e38f; else if (c1 == m) c1 = 3e38f;
        else if (c2 == m) c2 = 3e38f; else c3 = 3e38f;
      }
      thr = m;
    }
    if (t == 0) s_thr = thr;
  }
  __syncthreads();
  const float thr = s_thr;

  // --- pass 2: collect survivors (identical fma expr -> bitwise-consistent) ---
  if (SOA) {
    const int base = lo & ~3;
    for (int i0 = base + 4 * t; i0 < hi; i0 += 1024) {
      float4 vx = *(const float4*)&xs[i0];
      float4 vy = *(const float4*)&ys[i0];
      float4 vz = *(const float4*)&zs[i0];
#define ACC2(E, e)                                                              \
  { int i = i0 + E;                                                             \
    float dx = qx - vx.e, dy = qy - vy.e, dz = qz - vz.e;                       \
    float d2 = fmaf(dx, dx, fmaf(dy, dy, dz * dz));                             \
    if (i >= lo && i < hi && d2 <= thr) {                                       \
      int pos = atomicAdd(&s_cnt, 1);                                           \
      if (pos < SCAP)                                                           \
        s_cand[pos] = (((unsigned long long)__float_as_uint(d2)) << 32) | (unsigned)i; } }
      ACC2(0, x) ACC2(1, y) ACC2(2, z) ACC2(3, w)
#undef ACC2
    }
  } else {
    for (int i = lo + t; i < hi; i += 256) {
      float dx = qx - sxyz[3 * i], dy = qy - sxyz[3 * i + 1], dz = qz - sxyz[3 * i + 2];
      float d2 = fmaf(dx, dx, fmaf(dy, dy, dz * dz));
      if (d2 <= thr) {
        int pos = atomicAdd(&s_cnt, 1);
        if (pos < SCAP)
          s_cand[pos] = (((unsigned long long)__float_as_uint(d2)) << 32) | (unsigned)i;
      }
    }
  }
  __syncthreads();
  const int M = min(s_cnt, SCAP);

  // --- phase 3: exact top-16 extraction (d2>=0 -> raw-bit order; idx low-first) ---
  for (int r = 0; r < KNN; ++r) {
    if (t < 64) {
      unsigned long long lm = ~0ull; int ls = -1;
      for (int s = t; s < M; s += 64) {
        unsigned long long v = s_cand[s];
        if (v < lm) { lm = v; ls = s; }
      }
      unsigned long long g = lm;
      for (int off = 32; off; off >>= 1) {
        unsigned long long o = __shfl_xor(g, off, 64);
        if (o < g) g = o;
      }
      if (lm == g && ls >= 0 && g != ~0ull) {
        s_cand[ls] = ~0ull;
        col[q * KNN + r] = (int)(unsigned)(g & 0xffffffffull);
      }
    }
    __syncthreads();
  }
}

// ---------------------------------------------------------------------------
// Fused per-query kernel (128 threads): gathers, MLPs (W2 register-preloaded),
// norms, cosine dots, register/shuffle auction (wave 0, no LDS latency).
// ---------------------------------------------------------------------------
__global__ __launch_bounds__(128) void fused_kernel(
    const float* __restrict__ sxyz,
    const int* __restrict__ fidx,
    const float* __restrict__ gcn,
    const float* __restrict__ leaf,
    const float* __restrict__ W1, const float* __restrict__ b1,
    const float* __restrict__ W2, const float* __restrict__ b2,
    const float* __restrict__ Wl, const float* __restrict__ bl,
    const int* __restrict__ col,
    float* __restrict__ out) {
  const int q = blockIdx.x;
  const int t = threadIdx.x;

  __shared__ float s_edge[KNN * 130];
  __shared__ float s_cls[KNN * 130];
  __shared__ __align__(16) float s_hidden[KNN * 68];
  __shared__ float s_ew[KNN * 12];
  __shared__ float s_featC[KNN * 20];
  __shared__ int s_col[KNN];
  __shared__ float s_rna[24];
  __shared__ float s_rnb[3][KNN];
  __shared__ float s_mat[LROWS * 17];

  if (t < KNN) s_col[t] = col[q * KNN + t];
  __syncthreads();

  for (int v = t; v < KNN * 20; v += 128)
    s_featC[v] = gcn[(size_t)s_col[v / 20] * 148 + 128 + (v % 20)];
  if (t < KNN) {
    int fi = fidx[q];
    float qx = sxyz[3 * fi], qy = sxyz[3 * fi + 1], qz = sxyz[3 * fi + 2];
    int j = s_col[t];
    float jx = sxyz[3 * j], jy = sxyz[3 * j + 1], jz = sxyz[3 * j + 2];
    float dx = qx - jx, dy = qy - jy, dz = qz - jz;
    float dist = sqrtf(dx * dx + dy * dy + dz * dz);
    float* e = &s_ew[t * 12];
    e[0] = qx; e[1] = qy; e[2] = qz;
    e[3] = jx; e[4] = jy; e[5] = jz;
    e[6] = dx; e[7] = dy; e[8] = dz; e[9] = dist;
  }
  __syncthreads();

  // MLP layer 1
  for (int r = 0; r < 8; ++r) {
    int o = r * 128 + t;
    int k = o >> 6, j = o & 63;
    float acc0 = b1[j];
#pragma unroll
    for (int i = 0; i < 10; ++i) acc0 = fmaf(s_ew[k * 12 + i], W1[i * 64 + j], acc0);
    s_hidden[k * 68 + j] = fmaxf(acc0, 0.0f);
  }

  // Preload W2 column t (64 coalesced loads, latency hidden behind barrier)
  float w[64];
#pragma unroll
  for (int j = 0; j < 64; ++j) w[j] = W2[j * 128 + t];
  float acc[KNN];
#pragma unroll
  for (int k = 0; k < KNN; ++k) acc[k] = b2[t];
  __syncthreads();

  // MLP layer 2: pure fma on preloaded weights + broadcast b128 LDS reads
#pragma unroll 4
  for (int j4 = 0; j4 < 16; ++j4) {
#pragma unroll
    for (int k = 0; k < KNN; ++k) {
      float4 h = *(const float4*)&s_hidden[k * 68 + 4 * j4];
      acc[k] = fmaf(h.x, w[4 * j4 + 0], acc[k]);
      acc[k] = fmaf(h.y, w[4 * j4 + 1], acc[k]);
      acc[k] = fmaf(h.z, w[4 * j4 + 2], acc[k]);
      acc[k] = fmaf(h.w, w[4 * j4 + 3], acc[k]);
    }
  }
#pragma unroll
  for (int k = 0; k < KNN; ++k) s_edge[k * 130 + t] = acc[k];

  // cls GEMV
#pragma unroll
  for (int k = 0; k < KNN; ++k) acc[k] = bl[t];
#pragma unroll
  for (int c = 0; c < 20; ++c) {
    float wv = Wl[c * 128 + t];
#pragma unroll
    for (int k = 0; k < KNN; ++k) acc[k] = fmaf(s_featC[k * 20 + c], wv, acc[k]);
  }
#pragma unroll
  for (int k = 0; k < KNN; ++k) s_cls[k * 130 + t] = acc[k];
  __syncthreads();

  // 72 norm jobs
  if (t < 72) {
    float s0 = 0, s1 = 0, s2 = 0, s3 = 0;
    if (t < 24) {
      const float4* p = (const float4*)(leaf + (size_t)q * 3072 + (t / 3) * 384 + (t % 3) * 128);
#pragma unroll 4
      for (int h = 0; h < 32; ++h) {
        float4 v = p[h];
        s0 = fmaf(v.x, v.x, s0); s1 = fmaf(v.y, v.y, s1);
        s2 = fmaf(v.z, v.z, s2); s3 = fmaf(v.w, v.w, s3);
      }
    } else if (t < 56) {
      const float* p = (t < 40) ? &s_edge[(t - 24) * 130] : &s_cls[(t - 40) * 130];
#pragma unroll 4
      for (int h = 0; h < 128; h += 4) {
        float2 v0 = *(const float2*)&p[h];
        float2 v1 = *(const float2*)&p[h + 2];
        s0 = fmaf(v0.x, v0.x, s0); s1 = fmaf(v0.y, v0.y, s1);
        s2 = fmaf(v1.x, v1.x, s2); s3 = fmaf(v1.y, v1.y, s3);
      }
    } else {
      const float4* p = (const float4*)(gcn + (size_t)s_col[t - 56] * 148);
#pragma unroll 4
      for (int h = 0; h < 32; ++h) {
        float4 v = p[h];
        s0 = fmaf(v.x, v.x, s0); s1 = fmaf(v.y, v.y, s1);
        s2 = fmaf(v.z, v.z, s2); s3 = fmaf(v.w, v.w, s3);
      }
    }
    float rn = 1.0f / fmaxf(sqrtf((s0 + s1) + (s2 + s3)), 1e-8f);
    if (t < 24) s_rna[t] = rn;
    else if (t < 40) s_rnb[0][t - 24] = rn;
    else if (t < 56) s_rnb[1][t - 40] = rn;
    else s_rnb[2][t - 56] = rn;
  }
  __syncthreads();

  // 128 cosine dots -> mat
  {
    int l = t >> 4, k = t & 15;
    const float* a0 = leaf + (size_t)q * 3072 + l * 384;
    const float* bf = gcn + (size_t)s_col[k] * 148;
    const float* be = &s_edge[k * 130];
    const float* bc = &s_cls[k * 130];
    float d0 = 0, d1 = 0, d2 = 0;
    for (int h = 0; h < 128; h += 4) {
      float4 va0 = *(const float4*)&a0[h];
      float4 va1 = *(const float4*)&a0[128 + h];
      float4 va2 = *(const float4*)&a0[256 + h];
      float4 vbf = *(const float4*)&bf[h];
      float2 ve0 = *(const float2*)&be[h];
      float2 ve1 = *(const float2*)&be[h + 2];
      float2 vc0 = *(const float2*)&bc[h];
      float2 vc1 = *(const float2*)&bc[h + 2];
      d0 = fmaf(va0.x, ve0.x, d0); d0 = fmaf(va0.y, ve0.y, d0);
      d0 = fmaf(va0.z, ve1.x, d0); d0 = fmaf(va0.w, ve1.y, d0);
      d1 = fmaf(va1.x, vc0.x, d1); d1 = fmaf(va1.y, vc0.y, d1);
      d1 = fmaf(va1.z, vc1.x, d1); d1 = fmaf(va1.w, vc1.y, d1);
      d2 = fmaf(va2.x, vbf.x, d2); d2 = fmaf(va2.y, vbf.y, d2);
      d2 = fmaf(va2.z, vbf.z, d2); d2 = fmaf(va2.w, vbf.w, d2);
    }
    float m = (d0 * s_rna[l * 3 + 0] * s_rnb[0][k] +
               d1 * s_rna[l * 3 + 1] * s_rnb[1][k]) * 0.25f +
              d2 * s_rna[l * 3 + 2] * s_rnb[2][k] * 0.5f;
    s_mat[l * 17 + k] = m;
  }
  __syncthreads();

  if (t >= 64) return;  // wave 1 done; wave 0 runs the auction in registers

  // Register/shuffle synchronous-Jacobi auction. Lane r<8 = row state (ass),
  // lane c<16 = column state (cost, owner). All shuffles wave-uniform.
  float mrow[KNN];
#pragma unroll
  for (int c = 0; c < KNN; ++c) mrow[c] = s_mat[(t & 7) * 17 + c];
  int ass = -1;
  float cost = 0.f;

  for (int it = 0; it < 1024; ++it) {
    // row phase: top-2 of mrow - cost (lowest-col tie-break via strict >)
    float v1 = -3e38f, v2 = -3e38f; int c1 = 0;
#pragma unroll
    for (int c = 0; c < KNN; ++c) {
      float costc = __shfl(cost, c, 64);
      float v = mrow[c] - costc;
      if (v > v1) { v2 = v1; v1 = v; c1 = c; }
      else if (v > v2) v2 = v;
    }
    int bidc = (t < 8 && ass < 0) ? c1 : -1;
    float bidv = v1 - v2 + 0.125f;  // eps = 1/L

    // column phase: highest bid, lowest-row tie-break
    float high = -3e38f; int hb = -1;
#pragma unroll
    for (int r = 0; r < 8; ++r) {
      int bc = __shfl(bidc, r, 64);
      float bv = __shfl(bidv, r, 64);
      if (bc == t && bv > high) { high = bv; hb = r; }
    }
    if (t < 16 && hb >= 0) cost += high;

    int hb_c = __shfl(hb, bidc < 0 ? 0 : bidc, 64);  // did my bid win?
    int hb_a = __shfl(hb, ass < 0 ? 0 : ass, 64);    // was my column re-bid?
    if (t < 8) {
      if (ass >= 0 && hb_a >= 0) ass = -1;   // kicked
      if (bidc >= 0 && hb_c == t) ass = bidc; // won
    }
    if (__ballot((t < 8) ? (ass >= 0) : 1) == ~0ull) break;
  }

  float s = 0.f;
#pragma unroll
  for (int r = 0; r < 8; ++r) {
    int a = __shfl(ass, r, 64);
    if (t == 0) s += s_mat[r * 17 + a];
  }
  if (t == 0) out[q] = s * 0.125f;
}

// ---------------------------------------------------------------------------
extern "C" void kernel_launch(void* const* d_in, const int* in_sizes, int n_in,
                              void* d_out, int out_size, void* d_ws, size_t ws_size,
                              hipStream_t stream) {
  const float* sxyz = (const float*)d_in[0];
  const int* bidx = (const int*)d_in[1];
  const int* fidx = (const int*)d_in[2];
  const float* gcn = (const float*)d_in[3];
  const float* leaf = (const float*)d_in[4];
  const float* W1 = (const float*)d_in[5];
  const float* b1 = (const float*)d_in[6];
  const float* W2 = (const float*)d_in[7];
  const float* b2 = (const float*)d_in[8];
  const float* Wl = (const float*)d_in[9];
  const float* bl = (const float*)d_in[10];
  float* out = (float*)d_out;

  const int N = in_sizes[0] / 3;
  const int Q = in_sizes[2];
  const int NP = (N + 15) & ~15;

  // workspace layout
  char* ws = (char*)d_ws;
  size_t off = 0;
  int* col = (int*)(ws + off);      off += (size_t)Q * KNN * 4;
  float* qmeta = (float*)(ws + off); off += (size_t)Q * 8 * 4;
  int* starts = (int*)(ws + off);   off += 4096 * 4;
  int* ends = (int*)(ws + off);     off += 4096 * 4;
  float* xs = (float*)(ws + off);   off += (size_t)NP * 4;
  float* ys = (float*)(ws + off);   off += (size_t)NP * 4;
  float* zs = (float*)(ws + off);   off += (size_t)NP * 4;
  const bool soa = (ws_size >= off);

  if (soa) {
    prep_bounds<<<(N + 255) / 256, 256, 0, stream>>>(bidx, N, starts, ends);
    prep_soa<<<(NP + 255) / 256, 256, 0, stream>>>(sxyz, xs, ys, zs, N, NP);
    prep_qmeta<<<(Q + 255) / 256, 256, 0, stream>>>(sxyz, bidx, fidx, starts, ends, qmeta, Q);
    knn_kernel<true><<<Q, 256, 0, stream>>>(xs, ys, zs, qmeta, nullptr, nullptr, nullptr, col, N);
  } else {
    knn_kernel<false><<<Q, 256, 0, stream>>>(nullptr, nullptr, nullptr, nullptr,
                                             sxyz, bidx, fidx, col, N);
  }
  fused_kernel<<<Q, 128, 0, stream>>>(sxyz, fidx, gcn, leaf, W1, b1, W2, b2,
                                      Wl, bl, col, out);
}

// Round 4
// 496.132 us; speedup vs baseline: 1.0455x; 1.0455x over previous
//
#include <hip/hip_runtime.h>
#include <stdint.h>

#define KNN 16
#define LROWS 8
#define BQ 8      // queries per knn block
#define QCAP 128  // candidate cap per query (P(overflow) < 1e-40, rank-stat)

// ---------------------------------------------------------------------------
// Distance of 4 consecutive points (AoS float4x3 path). Same fmaf expression
// used in both passes -> bitwise-consistent d2.
// ---------------------------------------------------------------------------
__device__ __forceinline__ void dist4(const float* __restrict__ sxyz, int i0,
                                      int N, float qx, float qy, float qz,
                                      float out[4]) {
  float px[4], py[4], pz[4];
  if (i0 + 4 <= N) {
    float4 v0 = *(const float4*)&sxyz[3 * i0];
    float4 v1 = *(const float4*)&sxyz[3 * i0 + 4];
    float4 v2 = *(const float4*)&sxyz[3 * i0 + 8];
    px[0] = v0.x; py[0] = v0.y; pz[0] = v0.z;
    px[1] = v0.w; py[1] = v1.x; pz[1] = v1.y;
    px[2] = v1.z; py[2] = v1.w; pz[2] = v2.x;
    px[3] = v2.y; py[3] = v2.z; pz[3] = v2.w;
  } else {
#pragma unroll
    for (int e = 0; e < 4; ++e) {
      int i = i0 + e; bool ok = i < N;
      px[e] = ok ? sxyz[3 * i] : 0.f;
      py[e] = ok ? sxyz[3 * i + 1] : 0.f;
      pz[e] = ok ? sxyz[3 * i + 2] : 0.f;
    }
  }
#pragma unroll
  for (int e = 0; e < 4; ++e) {
    float dx = qx - px[e], dy = qy - py[e], dz = qz - pz[e];
    out[e] = fmaf(dx, dx, fmaf(dy, dy, dz * dz));
  }
}

// ---------------------------------------------------------------------------
// KNN: 8 queries / 128-thread block; 16 threads per query (one wave holds 4
// queries -> all per-query coordination is intra-wave shuffles, 1 barrier).
// Pass 1: 128 group minima per query (8 regs x 16 threads); threshold = 16th
// smallest (provable upper bound on true 16th-NN d2: >=16 disjoint groups
// with min <= thr => >=16 points <= thr). Pass 2: collect survivors (~17
// expected). Extraction: exact top-16 by packed (d2,idx) key == lax.top_k.
// ---------------------------------------------------------------------------
__global__ __launch_bounds__(128) void knn_kernel(
    const float* __restrict__ sxyz, const int* __restrict__ bidx,
    const int* __restrict__ fidx, int* __restrict__ col, int N, int Q) {
  const int t = threadIdx.x;
  const int qbase = blockIdx.x * BQ;
  const int g = t >> 4, j = t & 15, gw = (t >> 4) & 3;  // group, lane-in-group

  __shared__ unsigned long long s_cand[BQ][QCAP];
  __shared__ int s_cnt[BQ];
  __shared__ float s_qx[BQ], s_qy[BQ], s_qz[BQ];
  __shared__ int s_lo[BQ], s_hi[BQ];

  // stage meta: t<8 -> xyz + lower bound, t in [8,16) -> upper bound
  if (t < 2 * BQ) {
    int qi = qbase + (t & (BQ - 1));
    if (qi < Q) {
      int fi = fidx[qi];
      int qb = bidx[fi];
      if (t < BQ) {
        s_qx[t] = sxyz[3 * fi]; s_qy[t] = sxyz[3 * fi + 1]; s_qz[t] = sxyz[3 * fi + 2];
        int a = 0, b = N;
        while (a < b) { int m = (a + b) >> 1; if (bidx[m] < qb) a = m + 1; else b = m; }
        s_lo[t] = a;
      } else {
        int a = 0, b = N;
        while (a < b) { int m = (a + b) >> 1; if (bidx[m] <= qb) a = m + 1; else b = m; }
        s_hi[t - BQ] = a;
      }
    } else {
      if (t < BQ) { s_lo[t] = 0; s_qx[t] = s_qy[t] = s_qz[t] = 0.f; }
      else s_hi[t - BQ] = 0;
    }
  }
  if (t < BQ) s_cnt[t] = 0;
  __syncthreads();

  const float qx = s_qx[g], qy = s_qy[g], qz = s_qz[g];
  const int lo = s_lo[g], hi = s_hi[g];
  const int base = lo & ~3;

  // --- pass 1: 8 subgroup minima per thread (128 groups per query) ---
  float g0 = 3e38f, g1 = 3e38f, g2 = 3e38f, g3 = 3e38f,
        g4 = 3e38f, g5 = 3e38f, g6 = 3e38f, g7 = 3e38f;
  {
    int i0 = base + 4 * j;
#define STEP(M)                                                       \
    if (i0 < hi) {                                                    \
      float d2[4]; dist4(sxyz, i0, N, qx, qy, qz, d2);                \
      _Pragma("unroll")                                               \
      for (int e = 0; e < 4; ++e) {                                   \
        int i = i0 + e;                                               \
        float v = (i >= lo && i < hi) ? d2[e] : 3e38f;                \
        M = fminf(M, v);                                              \
      }                                                               \
    }                                                                 \
    i0 += 64;
    while (i0 < hi) {
      STEP(g0) STEP(g1) STEP(g2) STEP(g3) STEP(g4) STEP(g5) STEP(g6) STEP(g7)
    }
#undef STEP
  }

  // --- threshold: 16th smallest of the 128 group minima (intra-group shfl) ---
  float thr = 3e38f;
  for (int r = 0; r < KNN; ++r) {
    float lm = fminf(fminf(fminf(g0, g1), fminf(g2, g3)),
                     fminf(fminf(g4, g5), fminf(g6, g7)));
    float gm = lm;
    gm = fminf(gm, __shfl_xor(gm, 1, 64));
    gm = fminf(gm, __shfl_xor(gm, 2, 64));
    gm = fminf(gm, __shfl_xor(gm, 4, 64));
    gm = fminf(gm, __shfl_xor(gm, 8, 64));
    unsigned long long b = __ballot(lm == gm);
    int mask16 = (int)((b >> (gw * 16)) & 0xffffull);
    int win = __ffs((unsigned)mask16) - 1;
    if (j == win) {  // knock exactly one instance
      if (g0 == gm) g0 = 3e38f; else if (g1 == gm) g1 = 3e38f;
      else if (g2 == gm) g2 = 3e38f; else if (g3 == gm) g3 = 3e38f;
      else if (g4 == gm) g4 = 3e38f; else if (g5 == gm) g5 = 3e38f;
      else if (g6 == gm) g6 = 3e38f; else g7 = 3e38f;
    }
    thr = gm;
  }
  if (hi - lo <= QCAP) thr = 3e38f;  // tiny-segment exact fallback

  // --- pass 2: collect survivors ---
  for (int i0 = base + 4 * j; i0 < hi; i0 += 64) {
    float d2[4]; dist4(sxyz, i0, N, qx, qy, qz, d2);
#pragma unroll
    for (int e = 0; e < 4; ++e) {
      int i = i0 + e;
      if (i >= lo && i < hi && d2[e] <= thr) {
        int pos = atomicAdd(&s_cnt[g], 1);
        if (pos < QCAP)
          s_cand[g][pos] =
              (((unsigned long long)__float_as_uint(d2[e])) << 32) | (unsigned)i;
      }
    }
  }
  // group is intra-wave -> LDS ops in order, no barrier needed
  const int M = min(s_cnt[g], QCAP);

  // --- extraction: 16 rounds of exact group-min (keys unique) ---
  for (int r = 0; r < KNN; ++r) {
    unsigned long long lm = ~0ull; int ls = -1;
    for (int s = j; s < M; s += 16) {
      unsigned long long v = s_cand[g][s];
      if (v < lm) { lm = v; ls = s; }
    }
    unsigned long long gm = lm, o;
    o = __shfl_xor(gm, 1, 64); if (o < gm) gm = o;
    o = __shfl_xor(gm, 2, 64); if (o < gm) gm = o;
    o = __shfl_xor(gm, 4, 64); if (o < gm) gm = o;
    o = __shfl_xor(gm, 8, 64); if (o < gm) gm = o;
    unsigned long long b = __ballot(lm == gm);
    int mask16 = (int)((b >> (gw * 16)) & 0xffffull);
    int win = __ffs((unsigned)mask16) - 1;
    if (j == win && ls >= 0 && gm != ~0ull) {
      s_cand[g][ls] = ~0ull;
      col[(size_t)(qbase + g) * KNN + r] = (int)(unsigned)(gm & 0xffffffffull);
    }
  }
}

// ---------------------------------------------------------------------------
// Fused per-query kernel (128 threads). W2 preloaded into TRUE registers
// (fully unrolled consume loop -- R3's "#pragma unroll 4" left dynamic
// indexing and spilled 256 MB to scratch). Auction: wave 0, registers+shfl.
// ---------------------------------------------------------------------------
__global__ __launch_bounds__(128) void fused_kernel(
    const float* __restrict__ sxyz,
    const int* __restrict__ fidx,
    const float* __restrict__ gcn,
    const float* __restrict__ leaf,
    const float* __restrict__ W1, const float* __restrict__ b1,
    const float* __restrict__ W2, const float* __restrict__ b2,
    const float* __restrict__ Wl, const float* __restrict__ bl,
    const int* __restrict__ col,
    float* __restrict__ out) {
  const int q = blockIdx.x;
  const int t = threadIdx.x;

  __shared__ float s_edge[KNN * 130];
  __shared__ float s_cls[KNN * 130];
  __shared__ __align__(16) float s_hidden[KNN * 68];
  __shared__ float s_ew[KNN * 12];
  __shared__ float s_featC[KNN * 20];
  __shared__ int s_col[KNN];
  __shared__ float s_rna[24];
  __shared__ float s_rnb[3][KNN];
  __shared__ float s_mat[LROWS * 17];

  if (t < KNN) s_col[t] = col[q * KNN + t];
  __syncthreads();

  for (int v = t; v < KNN * 20; v += 128)
    s_featC[v] = gcn[(size_t)s_col[v / 20] * 148 + 128 + (v % 20)];
  if (t < KNN) {
    int fi = fidx[q];
    float qx = sxyz[3 * fi], qy = sxyz[3 * fi + 1], qz = sxyz[3 * fi + 2];
    int j = s_col[t];
    float jx = sxyz[3 * j], jy = sxyz[3 * j + 1], jz = sxyz[3 * j + 2];
    float dx = qx - jx, dy = qy - jy, dz = qz - jz;
    float dist = sqrtf(dx * dx + dy * dy + dz * dz);
    float* e = &s_ew[t * 12];
    e[0] = qx; e[1] = qy; e[2] = qz;
    e[3] = jx; e[4] = jy; e[5] = jz;
    e[6] = dx; e[7] = dy; e[8] = dz; e[9] = dist;
  }
  __syncthreads();

  // MLP layer 1
  for (int r = 0; r < 8; ++r) {
    int o = r * 128 + t;
    int k = o >> 6, jj = o & 63;
    float acc0 = b1[jj];
#pragma unroll
    for (int i = 0; i < 10; ++i) acc0 = fmaf(s_ew[k * 12 + i], W1[i * 64 + jj], acc0);
    s_hidden[k * 68 + jj] = fmaxf(acc0, 0.0f);
  }

  // Preload W2 column t into registers (latency hidden behind barrier)
  float w[64];
#pragma unroll
  for (int jj = 0; jj < 64; ++jj) w[jj] = W2[jj * 128 + t];
  float acc[KNN];
#pragma unroll
  for (int k = 0; k < KNN; ++k) acc[k] = b2[t];
  __syncthreads();

  // MLP layer 2: FULL unroll -> w[] indices compile-time -> registers
#pragma unroll
  for (int j4 = 0; j4 < 16; ++j4) {
#pragma unroll
    for (int k = 0; k < KNN; ++k) {
      float4 h = *(const float4*)&s_hidden[k * 68 + 4 * j4];
      acc[k] = fmaf(h.x, w[4 * j4 + 0], acc[k]);
      acc[k] = fmaf(h.y, w[4 * j4 + 1], acc[k]);
      acc[k] = fmaf(h.z, w[4 * j4 + 2], acc[k]);
      acc[k] = fmaf(h.w, w[4 * j4 + 3], acc[k]);
    }
  }
#pragma unroll
  for (int k = 0; k < KNN; ++k) s_edge[k * 130 + t] = acc[k];

  // cls GEMV
#pragma unroll
  for (int k = 0; k < KNN; ++k) acc[k] = bl[t];
#pragma unroll
  for (int c = 0; c < 20; ++c) {
    float wv = Wl[c * 128 + t];
#pragma unroll
    for (int k = 0; k < KNN; ++k) acc[k] = fmaf(s_featC[k * 20 + c], wv, acc[k]);
  }
#pragma unroll
  for (int k = 0; k < KNN; ++k) s_cls[k * 130 + t] = acc[k];
  __syncthreads();

  // 72 norm jobs
  if (t < 72) {
    float s0 = 0, s1 = 0, s2 = 0, s3 = 0;
    if (t < 24) {
      const float4* p = (const float4*)(leaf + (size_t)q * 3072 + (t / 3) * 384 + (t % 3) * 128);
#pragma unroll 4
      for (int h = 0; h < 32; ++h) {
        float4 v = p[h];
        s0 = fmaf(v.x, v.x, s0); s1 = fmaf(v.y, v.y, s1);
        s2 = fmaf(v.z, v.z, s2); s3 = fmaf(v.w, v.w, s3);
      }
    } else if (t < 56) {
      const float* p = (t < 40) ? &s_edge[(t - 24) * 130] : &s_cls[(t - 40) * 130];
#pragma unroll 4
      for (int h = 0; h < 128; h += 4) {
        float2 v0 = *(const float2*)&p[h];
        float2 v1 = *(const float2*)&p[h + 2];
        s0 = fmaf(v0.x, v0.x, s0); s1 = fmaf(v0.y, v0.y, s1);
        s2 = fmaf(v1.x, v1.x, s2); s3 = fmaf(v1.y, v1.y, s3);
      }
    } else {
      const float4* p = (const float4*)(gcn + (size_t)s_col[t - 56] * 148);
#pragma unroll 4
      for (int h = 0; h < 32; ++h) {
        float4 v = p[h];
        s0 = fmaf(v.x, v.x, s0); s1 = fmaf(v.y, v.y, s1);
        s2 = fmaf(v.z, v.z, s2); s3 = fmaf(v.w, v.w, s3);
      }
    }
    float rn = 1.0f / fmaxf(sqrtf((s0 + s1) + (s2 + s3)), 1e-8f);
    if (t < 24) s_rna[t] = rn;
    else if (t < 40) s_rnb[0][t - 24] = rn;
    else if (t < 56) s_rnb[1][t - 40] = rn;
    else s_rnb[2][t - 56] = rn;
  }
  __syncthreads();

  // 128 cosine dots -> mat
  {
    int l = t >> 4, k = t & 15;
    const float* a0 = leaf + (size_t)q * 3072 + l * 384;
    const float* bf = gcn + (size_t)s_col[k] * 148;
    const float* be = &s_edge[k * 130];
    const float* bc = &s_cls[k * 130];
    float d0 = 0, d1 = 0, d2 = 0;
    for (int h = 0; h < 128; h += 4) {
      float4 va0 = *(const float4*)&a0[h];
      float4 va1 = *(const float4*)&a0[128 + h];
      float4 va2 = *(const float4*)&a0[256 + h];
      float4 vbf = *(const float4*)&bf[h];
      float2 ve0 = *(const float2*)&be[h];
      float2 ve1 = *(const float2*)&be[h + 2];
      float2 vc0 = *(const float2*)&bc[h];
      float2 vc1 = *(const float2*)&bc[h + 2];
      d0 = fmaf(va0.x, ve0.x, d0); d0 = fmaf(va0.y, ve0.y, d0);
      d0 = fmaf(va0.z, ve1.x, d0); d0 = fmaf(va0.w, ve1.y, d0);
      d1 = fmaf(va1.x, vc0.x, d1); d1 = fmaf(va1.y, vc0.y, d1);
      d1 = fmaf(va1.z, vc1.x, d1); d1 = fmaf(va1.w, vc1.y, d1);
      d2 = fmaf(va2.x, vbf.x, d2); d2 = fmaf(va2.y, vbf.y, d2);
      d2 = fmaf(va2.z, vbf.z, d2); d2 = fmaf(va2.w, vbf.w, d2);
    }
    float m = (d0 * s_rna[l * 3 + 0] * s_rnb[0][k] +
               d1 * s_rna[l * 3 + 1] * s_rnb[1][k]) * 0.25f +
              d2 * s_rna[l * 3 + 2] * s_rnb[2][k] * 0.5f;
    s_mat[l * 17 + k] = m;
  }
  __syncthreads();

  if (t >= 64) return;  // wave 1 done; wave 0 runs the auction in registers

  float mrow[KNN];
#pragma unroll
  for (int c = 0; c < KNN; ++c) mrow[c] = s_mat[(t & 7) * 17 + c];
  int ass = -1;
  float cost = 0.f;

  for (int it = 0; it < 1024; ++it) {
    float v1 = -3e38f, v2 = -3e38f; int c1 = 0;
#pragma unroll
    for (int c = 0; c < KNN; ++c) {
      float costc = __shfl(cost, c, 64);
      float v = mrow[c] - costc;
      if (v > v1) { v2 = v1; v1 = v; c1 = c; }   // lowest-col tie-break
      else if (v > v2) v2 = v;
    }
    int bidc = (t < 8 && ass < 0) ? c1 : -1;
    float bidv = v1 - v2 + 0.125f;  // eps = 1/L

    float high = -3e38f; int hb = -1;
#pragma unroll
    for (int r = 0; r < 8; ++r) {
      int bc = __shfl(bidc, r, 64);
      float bv = __shfl(bidv, r, 64);
      if (bc == t && bv > high) { high = bv; hb = r; }  // lowest-row tie-break
    }
    if (t < 16 && hb >= 0) cost += high;

    int hb_c = __shfl(hb, bidc < 0 ? 0 : bidc, 64);
    int hb_a = __shfl(hb, ass < 0 ? 0 : ass, 64);
    if (t < 8) {
      if (ass >= 0 && hb_a >= 0) ass = -1;     // kicked
      if (bidc >= 0 && hb_c == t) ass = bidc;  // won
    }
    if (__ballot((t < 8) ? (ass >= 0) : 1) == ~0ull) break;
  }

  float s = 0.f;
#pragma unroll
  for (int r = 0; r < 8; ++r) {
    int a = __shfl(ass, r, 64);
    if (t == 0) s += s_mat[r * 17 + a];
  }
  if (t == 0) out[q] = s * 0.125f;
}

// ---------------------------------------------------------------------------
extern "C" void kernel_launch(void* const* d_in, const int* in_sizes, int n_in,
                              void* d_out, int out_size, void* d_ws, size_t ws_size,
                              hipStream_t stream) {
  const float* sxyz = (const float*)d_in[0];
  const int* bidx = (const int*)d_in[1];
  const int* fidx = (const int*)d_in[2];
  const float* gcn = (const float*)d_in[3];
  const float* leaf = (const float*)d_in[4];
  const float* W1 = (const float*)d_in[5];
  const float* b1 = (const float*)d_in[6];
  const float* W2 = (const float*)d_in[7];
  const float* b2 = (const float*)d_in[8];
  const float* Wl = (const float*)d_in[9];
  const float* bl = (const float*)d_in[10];
  float* out = (float*)d_out;

  const int N = in_sizes[0] / 3;
  const int Q = in_sizes[2];

  int* col = (int*)d_ws;  // Q*16 ints

  knn_kernel<<<(Q + BQ - 1) / BQ, 128, 0, stream>>>(sxyz, bidx, fidx, col, N, Q);
  fused_kernel<<<Q, 128, 0, stream>>>(sxyz, fidx, gcn, leaf, W1, b1, W2, b2,
                                      Wl, bl, col, out);
}

// Round 5
// 385.449 us; speedup vs baseline: 1.3457x; 1.2872x over previous
//
#include <hip/hip_runtime.h>
#include <stdint.h>

#define KNN 16
#define LROWS 8
#define KBQ 8     // queries per knn block
#define KCAP 128  // survivor cap per query (E[survivors]~17, rank-stat)

// ---------------------------------------------------------------------------
// Load 4 consecutive points (AoS, dense). Same fmaf d2 expression everywhere
// -> bitwise-consistent between passes.
// ---------------------------------------------------------------------------
__device__ __forceinline__ void load4(const float* __restrict__ sxyz, int i0,
                                      int N, float px[4], float py[4],
                                      float pz[4]) {
  if (i0 + 4 <= N) {
    float4 v0 = *(const float4*)&sxyz[3 * i0];
    float4 v1 = *(const float4*)&sxyz[3 * i0 + 4];
    float4 v2 = *(const float4*)&sxyz[3 * i0 + 8];
    px[0] = v0.x; py[0] = v0.y; pz[0] = v0.z;
    px[1] = v0.w; py[1] = v1.x; pz[1] = v1.y;
    px[2] = v1.z; py[2] = v1.w; pz[2] = v2.x;
    px[3] = v2.y; py[3] = v2.z; pz[3] = v2.w;
  } else {
#pragma unroll
    for (int e = 0; e < 4; ++e) {
      int i = i0 + e; bool ok = i < N;
      px[e] = ok ? sxyz[3 * i] : 0.f;
      py[e] = ok ? sxyz[3 * i + 1] : 0.f;
      pz[e] = ok ? sxyz[3 * i + 2] : 0.f;
    }
  }
}

// ---------------------------------------------------------------------------
// KNN: point-parallel, query-broadcast. 256 threads, 8 queries per block.
// Each thread loads points ONCE (dense coalesced) and tests vs all 8 queries
// in registers. Threshold per query = 16th smallest of the 256 per-thread
// minima (provable upper bound on the true 16th-NN d2: >=16 disjoint groups
// with min<=thr => >=16 points <= thr). Pass 2 collects survivors (~17);
// exact top-16 by packed (d2,idx) key == lax.top_k tie semantics.
// ---------------------------------------------------------------------------
__global__ __launch_bounds__(256) void knn_kernel(
    const float* __restrict__ sxyz, const int* __restrict__ bidx,
    const int* __restrict__ fidx, int* __restrict__ col, int N, int Q) {
  const int t = threadIdx.x;
  const int qbase = blockIdx.x * KBQ;

  __shared__ float s_min[KBQ][256];
  __shared__ unsigned long long s_cand[KBQ][KCAP];
  __shared__ int s_cnt[KBQ];
  __shared__ float s_thr[KBQ];
  __shared__ float s_qx[KBQ], s_qy[KBQ], s_qz[KBQ];
  __shared__ int s_lo[KBQ], s_hi[KBQ];

  // meta: t<8 -> xyz + lower bound, t in [8,16) -> upper bound
  if (t < 2 * KBQ) {
    int qi = qbase + (t & (KBQ - 1));
    if (qi < Q) {
      int fi = fidx[qi];
      int qb = bidx[fi];
      if (t < KBQ) {
        s_qx[t] = sxyz[3 * fi]; s_qy[t] = sxyz[3 * fi + 1]; s_qz[t] = sxyz[3 * fi + 2];
        int a = 0, b = N;
        while (a < b) { int m = (a + b) >> 1; if (bidx[m] < qb) a = m + 1; else b = m; }
        s_lo[t] = a;
      } else {
        int a = 0, b = N;
        while (a < b) { int m = (a + b) >> 1; if (bidx[m] <= qb) a = m + 1; else b = m; }
        s_hi[t - KBQ] = a;
      }
    } else {
      if (t < KBQ) { s_lo[t] = 0; s_qx[t] = s_qy[t] = s_qz[t] = 0.f; }
      else s_hi[t - KBQ] = 0;
    }
  }
  if (t < KBQ) s_cnt[t] = 0;
  __syncthreads();

  float qx[KBQ], qy[KBQ], qz[KBQ], qmin[KBQ];
  int qlo[KBQ], qhi[KBQ];
#pragma unroll
  for (int qi = 0; qi < KBQ; ++qi) {
    qx[qi] = s_qx[qi]; qy[qi] = s_qy[qi]; qz[qi] = s_qz[qi];
    qlo[qi] = s_lo[qi]; qhi[qi] = s_hi[qi];
    qmin[qi] = 3e38f;
  }
  int blo = qlo[0], bhi = qhi[0];
#pragma unroll
  for (int qi = 1; qi < KBQ; ++qi) { blo = min(blo, qlo[qi]); bhi = max(bhi, qhi[qi]); }
  const int base = blo & ~3;

  // --- pass 1: per-thread minima per query ---
  for (int i0 = base + 4 * t; i0 < bhi; i0 += 1024) {
    float px[4], py[4], pz[4];
    load4(sxyz, i0, N, px, py, pz);
#pragma unroll
    for (int e = 0; e < 4; ++e) {
      int i = i0 + e;
#pragma unroll
      for (int qi = 0; qi < KBQ; ++qi) {
        float dx = qx[qi] - px[e], dy = qy[qi] - py[e], dz = qz[qi] - pz[e];
        float d2 = fmaf(dx, dx, fmaf(dy, dy, dz * dz));
        bool v = (i >= qlo[qi]) && (i < qhi[qi]);
        qmin[qi] = fminf(qmin[qi], v ? d2 : 3e38f);
      }
    }
  }
#pragma unroll
  for (int qi = 0; qi < KBQ; ++qi) s_min[qi][t] = qmin[qi];
  __syncthreads();

  // --- threshold: 16th smallest of 256 minima; 32-thread group per query ---
  {
    int qi = t >> 5, u = t & 31;
    float v[8];
#pragma unroll
    for (int s = 0; s < 8; ++s) v[s] = s_min[qi][u + 32 * s];
    float thr = 3e38f;
    for (int r = 0; r < KNN; ++r) {
      float lm = fminf(fminf(fminf(v[0], v[1]), fminf(v[2], v[3])),
                       fminf(fminf(v[4], v[5]), fminf(v[6], v[7])));
      float gm = lm;
      gm = fminf(gm, __shfl_xor(gm, 1, 64));
      gm = fminf(gm, __shfl_xor(gm, 2, 64));
      gm = fminf(gm, __shfl_xor(gm, 4, 64));
      gm = fminf(gm, __shfl_xor(gm, 8, 64));
      gm = fminf(gm, __shfl_xor(gm, 16, 64));
      unsigned long long b = __ballot(lm == gm);
      unsigned mask = (unsigned)((b >> (t & 32)) & 0xffffffffull);
      int win = __ffs(mask) - 1;
      if (u == win) {  // knock exactly one instance
        if (v[0] == gm) v[0] = 3e38f; else if (v[1] == gm) v[1] = 3e38f;
        else if (v[2] == gm) v[2] = 3e38f; else if (v[3] == gm) v[3] = 3e38f;
        else if (v[4] == gm) v[4] = 3e38f; else if (v[5] == gm) v[5] = 3e38f;
        else if (v[6] == gm) v[6] = 3e38f; else v[7] = 3e38f;
      }
      thr = gm;
    }
    if (u == 0)
      s_thr[qi] = (s_hi[qi] - s_lo[qi] <= KCAP) ? 3e38f : thr;  // tiny-segment exact
  }
  __syncthreads();

  float qthr[KBQ];
#pragma unroll
  for (int qi = 0; qi < KBQ; ++qi) qthr[qi] = s_thr[qi];

  // --- pass 2: collect survivors ---
  for (int i0 = base + 4 * t; i0 < bhi; i0 += 1024) {
    float px[4], py[4], pz[4];
    load4(sxyz, i0, N, px, py, pz);
#pragma unroll
    for (int e = 0; e < 4; ++e) {
      int i = i0 + e;
#pragma unroll
      for (int qi = 0; qi < KBQ; ++qi) {
        float dx = qx[qi] - px[e], dy = qy[qi] - py[e], dz = qz[qi] - pz[e];
        float d2 = fmaf(dx, dx, fmaf(dy, dy, dz * dz));
        if (i >= qlo[qi] && i < qhi[qi] && d2 <= qthr[qi]) {
          int pos = atomicAdd(&s_cnt[qi], 1);
          if (pos < KCAP)
            s_cand[qi][pos] =
                (((unsigned long long)__float_as_uint(d2)) << 32) | (unsigned)i;
        }
      }
    }
  }
  __syncthreads();

  // --- extraction: 32-thread group per query, 16 exact min rounds ---
  {
    int qi = t >> 5, u = t & 31;
    int M = min(s_cnt[qi], KCAP);
    for (int r = 0; r < KNN; ++r) {
      unsigned long long lm = ~0ull; int ls = -1;
      for (int s = u; s < M; s += 32) {
        unsigned long long vv = s_cand[qi][s];
        if (vv < lm) { lm = vv; ls = s; }
      }
      unsigned long long gm = lm, o;
      o = __shfl_xor(gm, 1, 64); if (o < gm) gm = o;
      o = __shfl_xor(gm, 2, 64); if (o < gm) gm = o;
      o = __shfl_xor(gm, 4, 64); if (o < gm) gm = o;
      o = __shfl_xor(gm, 8, 64); if (o < gm) gm = o;
      o = __shfl_xor(gm, 16, 64); if (o < gm) gm = o;
      unsigned long long b = __ballot(lm == gm);
      unsigned mask = (unsigned)((b >> (t & 32)) & 0xffffffffull);
      int win = __ffs(mask) - 1;
      if (u == win && ls >= 0 && gm != ~0ull) {
        s_cand[qi][ls] = ~0ull;  // group is intra-wave -> in-order LDS, no barrier
        col[(size_t)(qbase + qi) * KNN + r] = (int)(unsigned)(gm & 0xffffffffull);
      }
    }
  }
}

// ---------------------------------------------------------------------------
// Fused per-query kernel (128 threads, 32.0 KB LDS -> 5 blocks/CU).
// Leaf staged to LDS once (coalesced); s_cls aliases s_hidden (dead after
// MLP2). EXT=true: dots write mat to workspace (auction in its own kernel).
// ---------------------------------------------------------------------------
#define OFF_LEAF 0     // 8 rows x stride 388 (pad: bank offset 4/row, 16B rows)
#define OFF_EDGE 3104  // 16 x 130
#define OFF_B 5184     // union: hidden 16x68 | cls 16x130
#define OFF_EW 7264    // 16 x 12
#define OFF_FC 7456    // 16 x 20
#define S_TOTAL 7776

template <bool EXT>
__global__ __launch_bounds__(128) void fused_kernel(
    const float* __restrict__ sxyz,
    const int* __restrict__ fidx,
    const float* __restrict__ gcn,
    const float* __restrict__ leaf,
    const float* __restrict__ W1, const float* __restrict__ b1,
    const float* __restrict__ W2, const float* __restrict__ b2,
    const float* __restrict__ Wl, const float* __restrict__ bl,
    const int* __restrict__ col,
    float* __restrict__ matw, float* __restrict__ out) {
  const int q = blockIdx.x;
  const int t = threadIdx.x;

  __shared__ __align__(16) float S[S_TOTAL];
  __shared__ int s_col[KNN];
  __shared__ float s_rna[24];
  __shared__ float s_rnb[3][KNN];
  __shared__ float s_mat[LROWS * 17];

  // --- stage leaf (12 KB) first: coalesced float4, latency hidden by MLP ---
  {
    const float4* lp = (const float4*)(leaf + (size_t)q * 3072);
#pragma unroll
    for (int r = 0; r < 6; ++r) {
      int v = r * 128 + t;
      float4 f = lp[v];
      int l = v / 96, off = (v % 96) * 4;
      *(float4*)&S[OFF_LEAF + l * 388 + off] = f;
    }
  }
  if (t < KNN) s_col[t] = col[q * KNN + t];
  __syncthreads();

  for (int v = t; v < KNN * 20; v += 128)
    S[OFF_FC + v] = gcn[(size_t)s_col[v / 20] * 148 + 128 + (v % 20)];
  if (t < KNN) {
    int fi = fidx[q];
    float qx = sxyz[3 * fi], qy = sxyz[3 * fi + 1], qz = sxyz[3 * fi + 2];
    int j = s_col[t];
    float jx = sxyz[3 * j], jy = sxyz[3 * j + 1], jz = sxyz[3 * j + 2];
    float dx = qx - jx, dy = qy - jy, dz = qz - jz;
    float dist = sqrtf(dx * dx + dy * dy + dz * dz);
    float* e = &S[OFF_EW + t * 12];
    e[0] = qx; e[1] = qy; e[2] = qz;
    e[3] = jx; e[4] = jy; e[5] = jz;
    e[6] = dx; e[7] = dy; e[8] = dz; e[9] = dist;
  }
  __syncthreads();

  // MLP layer 1 -> hidden (region B, stride 68)
  for (int r = 0; r < 8; ++r) {
    int o = r * 128 + t;
    int k = o >> 6, jj = o & 63;
    float acc0 = b1[jj];
#pragma unroll
    for (int i = 0; i < 10; ++i)
      acc0 = fmaf(S[OFF_EW + k * 12 + i], W1[i * 64 + jj], acc0);
    S[OFF_B + k * 68 + jj] = fmaxf(acc0, 0.0f);
  }
  __syncthreads();

  // MLP layer 2: W2 read in-loop (R2 style: 220us vs preload's 248us)
  float acc[KNN];
#pragma unroll
  for (int k = 0; k < KNN; ++k) acc[k] = b2[t];
#pragma unroll
  for (int j4 = 0; j4 < 16; ++j4) {
    float w0 = W2[(4 * j4 + 0) * 128 + t];
    float w1 = W2[(4 * j4 + 1) * 128 + t];
    float w2 = W2[(4 * j4 + 2) * 128 + t];
    float w3 = W2[(4 * j4 + 3) * 128 + t];
#pragma unroll
    for (int k = 0; k < KNN; ++k) {
      float4 h = *(const float4*)&S[OFF_B + k * 68 + 4 * j4];
      acc[k] = fmaf(h.x, w0, acc[k]);
      acc[k] = fmaf(h.y, w1, acc[k]);
      acc[k] = fmaf(h.z, w2, acc[k]);
      acc[k] = fmaf(h.w, w3, acc[k]);
    }
  }
#pragma unroll
  for (int k = 0; k < KNN; ++k) S[OFF_EDGE + k * 130 + t] = acc[k];
  __syncthreads();  // all threads done READING hidden before cls overwrites it

  // cls GEMV -> region B (stride 130), aliases dead hidden
#pragma unroll
  for (int k = 0; k < KNN; ++k) acc[k] = bl[t];
#pragma unroll
  for (int c = 0; c < 20; ++c) {
    float wv = Wl[c * 128 + t];
#pragma unroll
    for (int k = 0; k < KNN; ++k) acc[k] = fmaf(S[OFF_FC + k * 20 + c], wv, acc[k]);
  }
#pragma unroll
  for (int k = 0; k < KNN; ++k) S[OFF_B + k * 130 + t] = acc[k];
  __syncthreads();

  // 72 norm jobs (leaf/edge/cls from LDS; featH from global, warms L1 for dots)
  if (t < 72) {
    float s0 = 0, s1 = 0, s2 = 0, s3 = 0;
    if (t < 56) {
      const float* p;
      if (t < 24) p = &S[OFF_LEAF + (t / 3) * 388 + (t % 3) * 128];
      else if (t < 40) p = &S[OFF_EDGE + (t - 24) * 130];
      else p = &S[OFF_B + (t - 40) * 130];
#pragma unroll 4
      for (int h = 0; h < 128; h += 4) {
        float2 v0 = *(const float2*)&p[h];
        float2 v1 = *(const float2*)&p[h + 2];
        s0 = fmaf(v0.x, v0.x, s0); s1 = fmaf(v0.y, v0.y, s1);
        s2 = fmaf(v1.x, v1.x, s2); s3 = fmaf(v1.y, v1.y, s3);
      }
    } else {
      const float4* p = (const float4*)(gcn + (size_t)s_col[t - 56] * 148);
#pragma unroll 4
      for (int h = 0; h < 32; ++h) {
        float4 v = p[h];
        s0 = fmaf(v.x, v.x, s0); s1 = fmaf(v.y, v.y, s1);
        s2 = fmaf(v.z, v.z, s2); s3 = fmaf(v.w, v.w, s3);
      }
    }
    float rn = 1.0f / fmaxf(sqrtf((s0 + s1) + (s2 + s3)), 1e-8f);
    if (t < 24) s_rna[t] = rn;
    else if (t < 40) s_rnb[0][t - 24] = rn;
    else if (t < 56) s_rnb[1][t - 40] = rn;
    else s_rnb[2][t - 56] = rn;
  }
  __syncthreads();

  // 128 cosine dots -> mat (coalesced global store in EXT mode)
  {
    int l = t >> 4, k = t & 15;
    const float* a0 = &S[OFF_LEAF + l * 388];
    const float* be = &S[OFF_EDGE + k * 130];
    const float* bc = &S[OFF_B + k * 130];
    const float* bf = gcn + (size_t)s_col[k] * 148;
    float d0 = 0, d1 = 0, d2 = 0;
    for (int h = 0; h < 128; h += 4) {
      float4 va0 = *(const float4*)&a0[h];
      float4 va1 = *(const float4*)&a0[128 + h];
      float4 va2 = *(const float4*)&a0[256 + h];
      float4 vbf = *(const float4*)&bf[h];
      float2 ve0 = *(const float2*)&be[h];
      float2 ve1 = *(const float2*)&be[h + 2];
      float2 vc0 = *(const float2*)&bc[h];
      float2 vc1 = *(const float2*)&bc[h + 2];
      d0 = fmaf(va0.x, ve0.x, d0); d0 = fmaf(va0.y, ve0.y, d0);
      d0 = fmaf(va0.z, ve1.x, d0); d0 = fmaf(va0.w, ve1.y, d0);
      d1 = fmaf(va1.x, vc0.x, d1); d1 = fmaf(va1.y, vc0.y, d1);
      d1 = fmaf(va1.z, vc1.x, d1); d1 = fmaf(va1.w, vc1.y, d1);
      d2 = fmaf(va2.x, vbf.x, d2); d2 = fmaf(va2.y, vbf.y, d2);
      d2 = fmaf(va2.z, vbf.z, d2); d2 = fmaf(va2.w, vbf.w, d2);
    }
    float m = (d0 * s_rna[l * 3 + 0] * s_rnb[0][k] +
               d1 * s_rna[l * 3 + 1] * s_rnb[1][k]) * 0.25f +
              d2 * s_rna[l * 3 + 2] * s_rnb[2][k] * 0.5f;
    if (EXT) {
      matw[(size_t)q * 128 + t] = m;
      return;
    }
    s_mat[l * 17 + k] = m;
  }
  __syncthreads();
  if (t >= 64) return;

  // fallback inline auction (workspace too small for mat)
  float mrow[KNN];
#pragma unroll
  for (int c = 0; c < KNN; ++c) mrow[c] = s_mat[(t & 7) * 17 + c];
  int ass = -1;
  float cost = 0.f;
  for (int it = 0; it < 1024; ++it) {
    float v1 = -3e38f, v2 = -3e38f; int c1 = 0;
#pragma unroll
    for (int c = 0; c < KNN; ++c) {
      float costc = __shfl(cost, c, 64);
      float v = mrow[c] - costc;
      if (v > v1) { v2 = v1; v1 = v; c1 = c; }
      else if (v > v2) v2 = v;
    }
    int bidc = (t < 8 && ass < 0) ? c1 : -1;
    float bidv = v1 - v2 + 0.125f;
    float high = -3e38f; int hb = -1;
#pragma unroll
    for (int r = 0; r < 8; ++r) {
      int bc = __shfl(bidc, r, 64);
      float bv = __shfl(bidv, r, 64);
      if (bc == t && bv > high) { high = bv; hb = r; }
    }
    if (t < 16 && hb >= 0) cost += high;
    int hb_c = __shfl(hb, bidc < 0 ? 0 : bidc, 64);
    int hb_a = __shfl(hb, ass < 0 ? 0 : ass, 64);
    if (t < 8) {
      if (ass >= 0 && hb_a >= 0) ass = -1;
      if (bidc >= 0 && hb_c == t) ass = bidc;
    }
    if (__ballot((t < 8) ? (ass >= 0) : 1) == ~0ull) break;
  }
  float s = 0.f;
#pragma unroll
  for (int r = 0; r < 8; ++r) {
    int a = __shfl(ass, r, 64);
    if (t == 0) s += s_mat[r * 17 + a];
  }
  if (t == 0) out[q] = s * 0.125f;
}

// ---------------------------------------------------------------------------
// Auction kernel: 16 lanes per query (rows=lanes 0..7, cols=lanes 0..15),
// 4 queries/wave, 16/block. Pure register+shuffle synchronous Jacobi with
// exact reference tie-breaks (strict > scans: lowest col / lowest row).
// ---------------------------------------------------------------------------
__global__ __launch_bounds__(256) void auction_kernel(
    const float* __restrict__ matw, float* __restrict__ out, int Q) {
  const int t = threadIdx.x;
  const int lane = t & 63;
  const int gj = lane & 15;
  const int gb = lane & ~15;  // group base within wave
  const int q = blockIdx.x * 16 + (t >> 6) * 4 + (lane >> 4);
  const bool valid = q < Q;

  float mrow[KNN];
  if (valid && gj < 8) {
    const float4* mp = (const float4*)(matw + (size_t)q * 128 + gj * 16);
    float4 a = mp[0], b = mp[1], c = mp[2], d = mp[3];
    mrow[0] = a.x; mrow[1] = a.y; mrow[2] = a.z; mrow[3] = a.w;
    mrow[4] = b.x; mrow[5] = b.y; mrow[6] = b.z; mrow[7] = b.w;
    mrow[8] = c.x; mrow[9] = c.y; mrow[10] = c.z; mrow[11] = c.w;
    mrow[12] = d.x; mrow[13] = d.y; mrow[14] = d.z; mrow[15] = d.w;
  } else {
#pragma unroll
    for (int c = 0; c < KNN; ++c) mrow[c] = 0.f;
  }
  int ass = (valid && gj < 8) ? -1 : 0;  // cols/invalid lanes report "done"
  float cost = 0.f;

  for (int it = 0; it < 512; ++it) {
    float v1 = -3e38f, v2 = -3e38f; int c1 = 0;
#pragma unroll
    for (int c = 0; c < KNN; ++c) {
      float costc = __shfl(cost, gb + c, 64);
      float v = mrow[c] - costc;
      if (v > v1) { v2 = v1; v1 = v; c1 = c; }
      else if (v > v2) v2 = v;
    }
    int bidc = (valid && gj < 8 && ass < 0) ? c1 : -1;
    float bidv = v1 - v2 + 0.125f;  // eps = 1/L

    float high = -3e38f; int hb = -1;
#pragma unroll
    for (int r = 0; r < 8; ++r) {
      int bc = __shfl(bidc, gb + r, 64);
      float bv = __shfl(bidv, gb + r, 64);
      if (bc == gj && bv > high) { high = bv; hb = r; }
    }
    if (hb >= 0) cost += high;  // lane gj == column gj

    int hb_c = __shfl(hb, gb + (bidc < 0 ? 0 : bidc), 64);
    int hb_a = __shfl(hb, gb + (ass < 0 ? 0 : ass), 64);
    if (valid && gj < 8) {
      if (ass >= 0 && hb_a >= 0) ass = -1;     // kicked
      if (bidc >= 0 && hb_c == gj) ass = bidc; // won
    }
    if (__ballot(ass >= 0) == ~0ull) break;
  }

  float val = 0.f;
  if (valid && gj < 8) {
#pragma unroll
    for (int c = 0; c < KNN; ++c) val = (ass == c) ? mrow[c] : val;
  }
  val += __shfl_xor(val, 1, 64);
  val += __shfl_xor(val, 2, 64);
  val += __shfl_xor(val, 4, 64);
  if (valid && gj == 0) out[q] = val * 0.125f;
}

// ---------------------------------------------------------------------------
extern "C" void kernel_launch(void* const* d_in, const int* in_sizes, int n_in,
                              void* d_out, int out_size, void* d_ws, size_t ws_size,
                              hipStream_t stream) {
  const float* sxyz = (const float*)d_in[0];
  const int* bidx = (const int*)d_in[1];
  const int* fidx = (const int*)d_in[2];
  const float* gcn = (const float*)d_in[3];
  const float* leaf = (const float*)d_in[4];
  const float* W1 = (const float*)d_in[5];
  const float* b1 = (const float*)d_in[6];
  const float* W2 = (const float*)d_in[7];
  const float* b2 = (const float*)d_in[8];
  const float* Wl = (const float*)d_in[9];
  const float* bl = (const float*)d_in[10];
  float* out = (float*)d_out;

  const int N = in_sizes[0] / 3;
  const int Q = in_sizes[2];

  char* ws = (char*)d_ws;
  int* col = (int*)ws;
  float* matw = (float*)(ws + (size_t)Q * KNN * 4);
  const size_t need = (size_t)Q * KNN * 4 + (size_t)Q * 128 * 4;

  knn_kernel<<<(Q + KBQ - 1) / KBQ, 256, 0, stream>>>(sxyz, bidx, fidx, col, N, Q);
  if (ws_size >= need) {
    fused_kernel<true><<<Q, 128, 0, stream>>>(sxyz, fidx, gcn, leaf, W1, b1, W2,
                                              b2, Wl, bl, col, matw, out);
    auction_kernel<<<(Q + 15) / 16, 256, 0, stream>>>(matw, out, Q);
  } else {
    fused_kernel<false><<<Q, 128, 0, stream>>>(sxyz, fidx, gcn, leaf, W1, b1, W2,
                                               b2, Wl, bl, col, nullptr, out);
  }
}